// Round 6
// baseline (524.297 us; speedup 1.0000x reference)
//
#include <hip/hip_runtime.h>
#include <hip/hip_bf16.h>
#include <hip/hip_fp8.h>

typedef __attribute__((ext_vector_type(4))) float f32x4;
typedef __attribute__((ext_vector_type(2))) __bf16 bf16x2;

#define B_   16
#define C_   128
#define DIM  24
#define F_   128
#define OD   22
#define OS   (OD*OD*OD)        // 10648
#define SPB  (DIM*DIM*DIM)     // 13824 spatial per (b)
#define K_   3456              // 128*27
#define M_   (B_*OS)           // 170368  (= 64 * 2662 exactly, no tail)
#define OUTN (B_*F_*OS)        // 21807104
#define NSL  108               // 27 taps * 4 k-slices of 32

__device__ __forceinline__ unsigned char f2fp8(float v) {
  return __hip_fp8_e4m3(v).__x;            // OCP e4m3fn on gfx950
}

// ---------------- kernel 1: xs -> channels-last FP8 xt (natural c order),
// plus s1 = sum_c x^2. Row = 128 bytes, channel c at byte c.
__global__ __launch_bounds__(256) void prep_x(const float* __restrict__ xs,
                                              unsigned char* __restrict__ xt,
                                              float* __restrict__ s1) {
  __shared__ float tile[C_ * 97];            // 49.7 KB
  __shared__ float red[192];
  const int blk = blockIdx.x;                // (b*24+z)*6+yg, 2304 blocks
  const int yg = blk % 6;
  const int t2 = blk / 6;
  const int z = t2 % DIM;
  const int b = t2 / DIM;
  const int t = threadIdx.x;
  const float* src = xs + (size_t)b * C_ * SPB + z * (DIM * DIM) + yg * 96;
  for (int it = 0; it < 12; ++it) {
    int idx = it * 256 + t;
    int c = idx / 24, f4 = idx - c * 24;
    const float4 v = *(const float4*)(src + (size_t)c * SPB + f4 * 4);
    float* d = &tile[c * 97 + f4 * 4];
    d[0] = v.x; d[1] = v.y; d[2] = v.z; d[3] = v.w;
  }
  __syncthreads();
  // store fp8: 96 positions x 16 slots of 8 consecutive channels (8B stores)
  size_t obase = ((size_t)b * SPB + z * (DIM * DIM) + yg * 96) * C_;  // bytes
  for (int it = 0; it < 6; ++it) {
    int idx = it * 256 + t;
    int s = idx & 15, x = idx >> 4;
    unsigned int w0 = 0, w1 = 0;
#pragma unroll
    for (int j = 0; j < 4; ++j)
      w0 |= ((unsigned int)f2fp8(tile[(8 * s + j) * 97 + x])) << (8 * j);
#pragma unroll
    for (int j = 0; j < 4; ++j)
      w1 |= ((unsigned int)f2fp8(tile[(8 * s + 4 + j) * 97 + x])) << (8 * j);
    *(uint2*)&xt[obase + (size_t)x * C_ + s * 8] = make_uint2(w0, w1);
  }
  // s1: sum_c x^2 for the 96 positions (fp32)
  if (t < 192) {
    int g = t / 96, p = t - g * 96;
    float s = 0.f;
    for (int c = g; c < C_; c += 2) {
      float v = tile[c * 97 + p];
      s += v * v;
    }
    red[g * 96 + p] = s;
  }
  __syncthreads();
  if (t < 96)
    s1[((size_t)b * SPB + z * (DIM * DIM) + yg * 96) + t] = red[t] + red[96 + t];
}

// ---------------- kernel 2: weights -> FRAGMENT-PACKED fp8 Wt2 + ||p||^2 ----
// Wt2[((s*8 + g)*64 + l)*8 + j] = W[f = g*16 + (l&15)]
//                                  [k: tap = s>>2, c = (s&3)*32 + (l>>4)*8 + j]
// so one wave's A-fragment load (slice s, f-group g) is a CONTIGUOUS 512B run.
__global__ void prep_w(const float* __restrict__ fv,
                       unsigned char* __restrict__ Wt2,
                       float* __restrict__ psq) {
  __shared__ float tile[K_];                 // 13.8 KB
  const int f = blockIdx.x;                  // 128 blocks
  const float* src = fv + (size_t)f * K_;
  float part = 0.f;
  for (int idx = threadIdx.x; idx < K_; idx += 256) {
    float v = src[idx];                      // coalesced
    tile[idx] = v;
    part += v * v;
  }
  __syncthreads();
  const int g = f >> 4, fl = f & 15;
  for (int idx = threadIdx.x; idx < K_; idx += 256) {
    int tap = idx >> 7, c = idx & 127;       // fv index = c*27 + tap
    int kk = c >> 5, q = (c >> 3) & 3, j = c & 7;
    int s = tap * 4 + kk;
    int l = fl + (q << 4);
    Wt2[((size_t)(s * 8 + g) * 64 + l) * 8 + j] = f2fp8(tile[c * 27 + tap]);
  }
  for (int o = 32; o > 0; o >>= 1) part += __shfl_down(part, o, 64);
  __shared__ float red[4];
  int w = threadIdx.x >> 6, l = threadIdx.x & 63;
  if (l == 0) red[w] = part;
  __syncthreads();
  if (threadIdx.x == 0) psq[f] = red[0] + red[1] + red[2] + red[3];
}

// ---------------- kernel 3: 3x3x3 valid sum-pool of s1 ----------------------
__global__ void pool_sq(const float* __restrict__ s1, float* __restrict__ xsq) {
  int i = blockIdx.x * 256 + threadIdx.x;
  if (i >= M_) return;
  int ow = i % OD;
  int t = i / OD;
  int oh = t % OD; t /= OD;
  int od = t % OD;
  int b = t / OD;
  const float* p = s1 + ((b * DIM + od) * DIM + oh) * DIM + ow;
  float s = 0.f;
#pragma unroll
  for (int dz = 0; dz < 3; ++dz)
#pragma unroll
    for (int dy = 0; dy < 3; ++dy)
#pragma unroll
      for (int dx = 0; dx < 3; ++dx)
        s += p[dz * 576 + dy * 24 + dx];
  xsq[i] = s;
}

// ---------------- kernel 4: REGISTER-STREAMING fp8 MFMA + fused L2 epilogue -
// R6: NO LDS, NO BARRIERS. One wave = one independent 128f x 64m output tile,
// full K=3456. Rationale: five LDS-staged schedules (R0-R5) all pinned at
// MfmaUtil 22-29% with no pipe saturated -> the staging+lockstep structure
// itself is the cost. Here operands stream straight to registers:
//   A (weights): fragment-packed Wt2, 8 x global_load_dwordx2 per slice,
//       perfectly coalesced 512B runs; 432 KB total, L2-resident, shared.
//   B (patches): 4 x global_load_dwordx2 per slice, 16 rows x 32B from xt;
//       a wave's per-tap working set is 8 KB -> L1-resident across 4 slices.
// 32 independent accumulators (128 VGPR) -> 512 cyc of dependency-free MFMA
// per slice hides the next slice's load latency (reg double-buffer, unroll-2,
// static indexing per rule #20). 2 waves/SIMD via __launch_bounds__(64,2).
__global__ __launch_bounds__(64, 2) void l2gemm(
    const unsigned char* __restrict__ xt, const unsigned char* __restrict__ Wt2,
    const float* __restrict__ xsq, const float* __restrict__ psq,
    float* __restrict__ out) {
  const int l = threadIdx.x;                 // one wave per block
  const int lan = l & 15, quad = l >> 4;

  // bijective XCD-aware block swizzle (nwg=2662, 2662%8!=0)
  const int nwg = gridDim.x;
  const int orig = blockIdx.x;
  const int xcd = orig & 7, lo = orig >> 3;
  const int q = nwg >> 3, r = nwg & 7;
  const int mt = (xcd < r ? xcd * (q + 1) : r * (q + 1) + (xcd - r) * q) + lo;
  const int m0 = mt * 64;

  // per-lane B byte-offsets (within xt) for the 4 m-fragments
  int vof[4];
#pragma unroll
  for (int n = 0; n < 4; ++n) {
    int m = m0 + n * 16 + lan;
    int b = m / OS;
    int s = m - b * OS;
    int od = s / (OD * OD);
    int s2 = s - od * (OD * OD);
    int oh = s2 / OD;
    int ow = s2 - oh * OD;
    vof[n] = (b * SPB + od * 576 + oh * 24 + ow) * 128 + quad * 8;
  }
  const int aof = l * 8;                     // per-lane A offset within a slice

  f32x4 acc[8][4];
#pragma unroll
  for (int g = 0; g < 8; ++g)
#pragma unroll
    for (int n = 0; n < 4; ++n) acc[g][n] = (f32x4){0.f, 0.f, 0.f, 0.f};

  long A0[8], B0[4], A1[8], B1[4];

  auto LD = [&](long* A, long* B, int s) {
    int tap = s >> 2, k0 = (s & 3) << 5;
    int dz = tap / 9;
    int rem = tap - dz * 9;
    int dy = rem / 3;
    int dx = rem - dy * 3;
    const unsigned char* xp = xt + (dz * 576 + dy * 24 + dx) * 128 + k0;
    const unsigned char* ap = Wt2 + (size_t)s * 4096 + aof;
#pragma unroll
    for (int g = 0; g < 8; ++g) A[g] = *(const long*)(ap + g * 512);
#pragma unroll
    for (int n = 0; n < 4; ++n) B[n] = *(const long*)(xp + vof[n]);
  };
  auto MM = [&](long* A, long* B) {
#pragma unroll
    for (int g = 0; g < 8; ++g)
#pragma unroll
      for (int n = 0; n < 4; ++n)
        acc[g][n] = __builtin_amdgcn_mfma_f32_16x16x32_fp8_fp8(A[g], B[n],
                                                               acc[g][n], 0, 0, 0);
  };

  LD(A0, B0, 0);
#pragma unroll 1
  for (int s = 0; s < NSL; s += 2) {
    LD(A1, B1, s + 1);                       // prefetch odd slice
    MM(A0, B0);                              // compute even (hides the loads)
    if (s + 2 < NSL) LD(A0, B0, s + 2);      // prefetch next even slice
    MM(A1, B1);                              // compute odd
  }

  // epilogue: out[b][f][s] = sqrt(|xsq + psq - 2*dot| + eps)
  int mb[4];
  float xv[4];
#pragma unroll
  for (int n = 0; n < 4; ++n) {
    int m = m0 + n * 16 + lan;
    int b = m / OS;
    int s = m - b * OS;
    mb[n] = b * (F_ * OS) + s;
    xv[n] = xsq[m];
  }
#pragma unroll
  for (int g = 0; g < 8; ++g) {
#pragma unroll
    for (int r2 = 0; r2 < 4; ++r2) {
      int f = g * 16 + quad * 4 + r2;
      float pq = psq[f];
#pragma unroll
      for (int n = 0; n < 4; ++n) {
        float d = xv[n] + pq - 2.0f * acc[g][n][r2];
        out[mb[n] + f * OS] = sqrtf(fabsf(d) + 1e-14f);
      }
    }
  }
}

// ---------------- fallback: direct fp32 conv (only if ws too small) ---------
__global__ void l2conv_direct(const float* __restrict__ xs,
                              const float* __restrict__ fv,
                              float* __restrict__ out) {
  int i = blockIdx.x * 256 + threadIdx.x;
  if (i >= OUTN) return;
  int s = i % OS;
  int t2 = i / OS;
  int f = t2 & 127;
  int b = t2 >> 7;
  int od = s / (OD * OD);
  int s2 = s - od * (OD * OD);
  int oh = s2 / OD;
  int ow = s2 - oh * OD;
  const float* xp = xs + (size_t)b * C_ * SPB + od * 576 + oh * 24 + ow;
  const float* wp = fv + (size_t)f * K_;
  float dot = 0.f, xq = 0.f, pq = 0.f;
  for (int c = 0; c < C_; ++c) {
    const float* xpc = xp + (size_t)c * SPB;
    const float* wpc = wp + c * 27;
#pragma unroll
    for (int o = 0; o < 27; ++o) {
      int dz = o / 9;
      int ry = o - dz * 9;
      int dy = ry / 3;
      int dx = ry - dy * 3;
      float xv = xpc[dz * 576 + dy * 24 + dx];
      float wv = wpc[o];
      dot += xv * wv;
      xq += xv * xv;
      pq += wv * wv;
    }
  }
  out[i] = sqrtf(fabsf(xq + pq - 2.f * dot) + 1e-14f);
}

// ---------------- launch ----------------------------------------------------
extern "C" void kernel_launch(void* const* d_in, const int* in_sizes, int n_in,
                              void* d_out, int out_size, void* d_ws,
                              size_t ws_size, hipStream_t stream) {
  const float* xs = (const float*)d_in[0];
  const float* fv = (const float*)d_in[1];
  float* out = (float*)d_out;

  const size_t xt_b  = (size_t)B_ * SPB * C_;       // 28,311,552 (fp8)
  const size_t wt_b  = (size_t)F_ * K_;             //    442,368 (fp8 packed)
  const size_t s1_b  = (size_t)B_ * SPB * 4;        //    884,736
  const size_t xsq_b = (size_t)M_ * 4;              //    681,472
  const size_t psq_b = 512;
  if (ws_size < xt_b + wt_b + s1_b + xsq_b + psq_b) {
    l2conv_direct<<<(OUTN + 255) / 256, 256, 0, stream>>>(xs, fv, out);
    return;
  }
  char* p = (char*)d_ws;
  unsigned char* xt = (unsigned char*)p;  p += xt_b;
  unsigned char* Wt2 = (unsigned char*)p; p += wt_b;
  float* s1 = (float*)p;                  p += s1_b;
  float* xsq = (float*)p;                 p += xsq_b;
  float* psq = (float*)p;

  prep_x<<<B_ * DIM * DIM / 4, 256, 0, stream>>>(xs, xt, s1);
  prep_w<<<F_, 256, 0, stream>>>(fv, Wt2, psq);
  pool_sq<<<(M_ + 255) / 256, 256, 0, stream>>>(s1, xsq);
  l2gemm<<<M_ / 64, 64, 0, stream>>>(xt, Wt2, xsq, psq, out);
}

// Round 8
// 377.410 us; speedup vs baseline: 1.3892x; 1.3892x over previous
//
#include <hip/hip_runtime.h>
#include <hip/hip_bf16.h>

typedef __attribute__((ext_vector_type(8))) __bf16 bf16x8;
typedef __attribute__((ext_vector_type(4))) float f32x4;

#define B_   16
#define C_   128
#define DIM  24
#define F_   128
#define OD   22
#define OS   (OD*OD*OD)        // 10648
#define SPB  (DIM*DIM*DIM)     // 13824 spatial per (b)
#define K_   3456              // 128*27
#define M_   (B_*OS)           // 170368 = 1331 * 128 exactly
#define OUTN (B_*F_*OS)        // 21807104

// ---------------- async global->LDS (16B per lane, wave-uniform LDS base) ---
__device__ __forceinline__ void async16(const void* g, void* l) {
  __builtin_amdgcn_global_load_lds(
      (const __attribute__((address_space(1))) unsigned int*)g,
      (__attribute__((address_space(3))) unsigned int*)l, 16, 0, 0);
}

// ---------------- kernel 1: xs -> channels-last bf16 xt, plus sum_c x^2 -----
// v2: tile x-coord XOR-swizzled by channel-group (x ^= ((c>>3)&7)<<2, float4-
// aligned so the coalesced float4 load-phase writes stay contiguous 16B).
// Transposed read then hits 2 lanes/bank (free, m136) instead of 4-way, and
// the store loop emits 16B bf16x8 stores (6 iters) instead of 4B x 24 iters.
__global__ __launch_bounds__(256) void prep_x(const float* __restrict__ xs,
                                              __bf16* __restrict__ xt,
                                              float* __restrict__ s1) {
  __shared__ float tile[C_ * 97];            // 49.7 KB
  __shared__ float red[192];
  const int blk = blockIdx.x;                // (b*24+z)*6+yg, 2304 blocks
  const int yg = blk % 6;
  const int t2 = blk / 6;
  const int z = t2 % DIM;
  const int b = t2 / DIM;
  const int t = threadIdx.x;
  const float* src = xs + (size_t)b * C_ * SPB + z * (DIM * DIM) + yg * 96;
  // load: 128c x 24 float4 (96 contiguous floats per c), x-swizzled placement
  for (int it = 0; it < 12; ++it) {
    int idx = it * 256 + t;
    int c = idx / 24, f4 = idx - c * 24;
    const float4 v = *(const float4*)(src + (size_t)c * SPB + f4 * 4);
    int sw = (c >> 3) & 7;
    float* d = &tile[c * 97 + 4 * (f4 ^ sw)];  // pos x=4*f4+k at x^(sw<<2)
    d[0] = v.x; d[1] = v.y; d[2] = v.z; d[3] = v.w;
  }
  __syncthreads();
  // store transposed bf16: 96 pos x 16 groups of 8 channels, 16B per thread
  size_t obase = ((size_t)b * SPB + z * (DIM * DIM) + yg * 96) * C_;
  for (int it = 0; it < 6; ++it) {
    int idx = it * 256 + t;
    int g = idx & 15, x = idx >> 4;
    int xsw = x ^ ((g & 7) << 2);            // matches load-phase swizzle
    bf16x8 v;
#pragma unroll
    for (int j = 0; j < 8; ++j)
      v[j] = (__bf16)tile[(8 * g + j) * 97 + xsw];
    *(bf16x8*)&xt[obase + (size_t)x * C_ + 8 * g] = v;  // 16 lanes = 256B run
  }
  // s1: sum_c x^2 for the 96 positions, 2-way split over c
  if (t < 192) {
    int g = t / 96, p = t - g * 96;
    float s = 0.f;
    for (int c = g; c < C_; c += 2) {
      float v = tile[c * 97 + (p ^ (((c >> 3) & 7) << 2))];
      s += v * v;
    }
    red[g * 96 + p] = s;
  }
  __syncthreads();
  if (t < 96)
    s1[((size_t)b * SPB + z * (DIM * DIM) + yg * 96) + t] = red[t] + red[96 + t];
}

// ---------------- kernel 2: weights -> Wt[f][off*128+c] bf16, plus ||p||^2 --
__global__ void prep_w(const float* __restrict__ fv, __bf16* __restrict__ Wt,
                       float* __restrict__ psq) {
  __shared__ float tile[K_];                 // 13.8 KB
  const int f = blockIdx.x;                  // 128 blocks
  const float* src = fv + (size_t)f * K_;
  float part = 0.f;
  for (int idx = threadIdx.x; idx < K_; idx += 256) {
    float v = src[idx];                      // coalesced
    tile[idx] = v;
    part += v * v;
  }
  __syncthreads();
  for (int idx = threadIdx.x; idx < K_; idx += 256) {
    int c = idx & 127, off = idx >> 7;       // k = off*128 + c
    Wt[(size_t)f * K_ + idx] = (__bf16)tile[c * 27 + off];  // 27co32 coprime
  }
  for (int o = 32; o > 0; o >>= 1) part += __shfl_down(part, o, 64);
  __shared__ float red[4];
  int w = threadIdx.x >> 6, l = threadIdx.x & 63;
  if (l == 0) red[w] = part;
  __syncthreads();
  if (threadIdx.x == 0) psq[f] = red[0] + red[1] + red[2] + red[3];
}

// ---------------- kernel 3: implicit-GEMM MFMA + fused pool + L2 epilogue ---
// R8 = R1's proven double-buffered schedule (best measured: 219 us) verbatim,
// plus the 3x3x3 sum-pool of s1 fused into the prologue (R5-proven pattern;
// safe here because all waits are __syncthreads -> vmcnt(0) drains include
// the pool loads, no counted-vmcnt accounting to disturb).
__global__ __launch_bounds__(256) void l2gemm(
    const __bf16* __restrict__ xt, const __bf16* __restrict__ Wt,
    const float* __restrict__ s1, const float* __restrict__ psq,
    float* __restrict__ out) {
  __shared__ __align__(16) __bf16 Wl[2][128 * 64];   // 32 KB
  __shared__ __align__(16) __bf16 Pl[2][128 * 64];   // 32 KB
  __shared__ float xsql[128];                        // 0.5 KB
  const int t = threadIdx.x;
  const int l = t & 63, w = t >> 6;
  const int quad = l >> 4, lan = l & 15;
  const int e = t & 7, r0 = t >> 3;     // staging: chunk e (16B) of row r0+32p
  const int esw = (e ^ (r0 & 7)) * 8;   // XOR-swizzled source chunk (bf16)

  // bijective XCD-aware block swizzle (nwg=1331, 1331%8!=0)
  const int nwg = gridDim.x;
  const int orig = blockIdx.x;
  const int xcd = orig & 7, lo = orig >> 3;
  const int q = nwg >> 3, r = nwg & 7;
  const int mt = (xcd < r ? xcd * (q + 1) : r * (q + 1) + (xcd - r) * q) + lo;

  // spatial base for the 4 staged patch rows
  int sb[4];
#pragma unroll
  for (int p = 0; p < 4; ++p) {
    int m = mt * 128 + r0 + 32 * p;
    int b = m / OS;
    int s = m - b * OS;
    int od = s / (OD * OD);
    int s2 = s - od * (OD * OD);
    int oh = s2 / OD;
    int ow = s2 - oh * OD;
    sb[p] = b * SPB + od * 576 + oh * 24 + ow;
  }

  // fused 3x3x3 sum-pool of s1 for this block's 128 m's (L2-resident reads)
  if (t < 128) {
    int m = mt * 128 + t;
    int b = m / OS;
    int s = m - b * OS;
    int od = s / (OD * OD);
    int s2 = s - od * (OD * OD);
    int oh = s2 / OD;
    int ow = s2 - oh * OD;
    const float* pp = s1 + ((b * DIM + od) * DIM + oh) * DIM + ow;
    float ss = 0.f;
#pragma unroll
    for (int dz = 0; dz < 3; ++dz)
#pragma unroll
      for (int dy = 0; dy < 3; ++dy)
#pragma unroll
        for (int dx = 0; dx < 3; ++dx)
          ss += pp[dz * 576 + dy * 24 + dx];
    xsql[t] = ss;
  }

  f32x4 acc[4][4];
#pragma unroll
  for (int i = 0; i < 4; ++i)
#pragma unroll
    for (int n = 0; n < 4; ++n) acc[i][n] = (f32x4){0.f, 0.f, 0.f, 0.f};

  const int wm = (w >> 1) * 64;   // f-offset of this wave's 64x64 subtile
  const int wn = (w & 1) * 64;    // patch-offset
  const int wrow = w * 8;         // wave's 8-row staging base per 32-row group

  // stage K-tile kt into buffer buf (8 x global_load_lds_dwordx4 per thread)
  auto stage = [&](int kt, int buf) {
    int off = kt >> 1;
    int dz = off / 9;
    int rem = off - dz * 9;
    int dy = rem / 3;
    int dx = rem - dy * 3;
    int doff = dz * 576 + dy * 24 + dx;
    int c0 = (kt & 1) << 6;
    __bf16* wl = &Wl[buf][wrow * 64];
    __bf16* pl = &Pl[buf][wrow * 64];
#pragma unroll
    for (int p = 0; p < 4; ++p) {
      const __bf16* gp = xt + (((size_t)(sb[p] + doff)) << 7) + c0 + esw;
      async16(gp, pl + (size_t)(32 * p) * 64);
      const __bf16* gw = Wt + (size_t)(r0 + 32 * p) * K_ + kt * 64 + esw;
      async16(gw, wl + (size_t)(32 * p) * 64);
    }
  };

  stage(0, 0);
  __syncthreads();                 // vmcnt(0) drain + barrier: buf0 ready
  int cur = 0;
#pragma unroll 1
  for (int kt = 0; kt < 54; ++kt) {
    if (kt < 53) stage(kt + 1, cur ^ 1);   // prefetch next tile FIRST
    const __bf16* Wc = &Wl[cur][0];
    const __bf16* Pc = &Pl[cur][0];
#pragma unroll
    for (int kk = 0; kk < 2; ++kk) {
      bf16x8 a[4], bb[4];
      const int swz = (((kk * 4 + quad) ^ (lan & 7))) * 8;  // read-side XOR
#pragma unroll
      for (int i = 0; i < 4; ++i)
        a[i] = *(const bf16x8*)&Wc[(wm + i * 16 + lan) * 64 + swz];
#pragma unroll
      for (int n = 0; n < 4; ++n)
        bb[n] = *(const bf16x8*)&Pc[(wn + n * 16 + lan) * 64 + swz];
#pragma unroll
      for (int i = 0; i < 4; ++i)
#pragma unroll
        for (int n = 0; n < 4; ++n)
          acc[i][n] = __builtin_amdgcn_mfma_f32_16x16x32_bf16(a[i], bb[n],
                                                              acc[i][n], 0, 0, 0);
    }
    __syncthreads();               // drains new stage's vmcnt + barrier
    cur ^= 1;
  }

  // epilogue: out[b][f][s] = sqrt(|xsq + psq - 2*dot| + eps)
  int mb[4];
  float xv[4];
#pragma unroll
  for (int n = 0; n < 4; ++n) {
    int m = mt * 128 + wn + n * 16 + lan;
    int b = m / OS;
    int s = m - b * OS;
    mb[n] = b * (F_ * OS) + s;
    xv[n] = xsql[wn + n * 16 + lan];
  }
#pragma unroll
  for (int i = 0; i < 4; ++i) {
#pragma unroll
    for (int r2 = 0; r2 < 4; ++r2) {
      int f = wm + i * 16 + quad * 4 + r2;
      float pq = psq[f];
#pragma unroll
      for (int n = 0; n < 4; ++n) {
        float d = xv[n] + pq - 2.0f * acc[i][n][r2];
        out[mb[n] + f * OS] = sqrtf(fabsf(d) + 1e-14f);
      }
    }
  }
}

// ---------------- fallback: direct fp32 conv (only if ws too small) ---------
__global__ void l2conv_direct(const float* __restrict__ xs,
                              const float* __restrict__ fv,
                              float* __restrict__ out) {
  int i = blockIdx.x * 256 + threadIdx.x;
  if (i >= OUTN) return;
  int s = i % OS;
  int t2 = i / OS;
  int f = t2 & 127;
  int b = t2 >> 7;
  int od = s / (OD * OD);
  int s2 = s - od * (OD * OD);
  int oh = s2 / OD;
  int ow = s2 - oh * OD;
  const float* xp = xs + (size_t)b * C_ * SPB + od * 576 + oh * 24 + ow;
  const float* wp = fv + (size_t)f * K_;
  float dot = 0.f, xq = 0.f, pq = 0.f;
  for (int c = 0; c < C_; ++c) {
    const float* xpc = xp + (size_t)c * SPB;
    const float* wpc = wp + c * 27;
#pragma unroll
    for (int o = 0; o < 27; ++o) {
      int dz = o / 9;
      int ry = o - dz * 9;
      int dy = ry / 3;
      int dx = ry - dy * 3;
      float xv = xpc[dz * 576 + dy * 24 + dx];
      float wv = wpc[o];
      dot += xv * wv;
      xq += xv * xv;
      pq += wv * wv;
    }
  }
  out[i] = sqrtf(fabsf(xq + pq - 2.f * dot) + 1e-14f);
}

// ---------------- launch ----------------------------------------------------
extern "C" void kernel_launch(void* const* d_in, const int* in_sizes, int n_in,
                              void* d_out, int out_size, void* d_ws,
                              size_t ws_size, hipStream_t stream) {
  const float* xs = (const float*)d_in[0];
  const float* fv = (const float*)d_in[1];
  float* out = (float*)d_out;

  const size_t xt_b  = (size_t)B_ * SPB * C_ * 2;   // 56,623,104
  const size_t wt_b  = (size_t)F_ * K_ * 2;         //    884,736
  const size_t s1_b  = (size_t)B_ * SPB * 4;        //    884,736
  const size_t psq_b = 512;
  if (ws_size < xt_b + wt_b + s1_b + psq_b) {
    l2conv_direct<<<(OUTN + 255) / 256, 256, 0, stream>>>(xs, fv, out);
    return;
  }
  char* p = (char*)d_ws;
  __bf16* xt = (__bf16*)p;          p += xt_b;
  __bf16* Wt = (__bf16*)p;          p += wt_b;
  float*  s1 = (float*)p;           p += s1_b;
  float*  psq = (float*)p;

  prep_x<<<B_ * DIM * DIM / 4, 256, 0, stream>>>(xs, xt, s1);
  prep_w<<<F_, 256, 0, stream>>>(fv, Wt, psq);
  l2gemm<<<M_ / 128, 256, 0, stream>>>(xt, Wt, s1, psq, out);
}